// Round 5
// baseline (6529.222 us; speedup 1.0000x reference)
//
#include <hip/hip_runtime.h>
#include <hip/hip_bf16.h>
#include <hip/hip_cooperative_groups.h>
#include <cstddef>

namespace cg = cooperative_groups;

// Problem dims (fixed)
#define BB 256
#define CC 512
#define SS 128      // FH*FW = 8*16
#define HH 512
#define VV 64
#define LL 24       // sequence length; steps = 23

typedef unsigned short ush;
typedef __attribute__((ext_vector_type(8))) short short8;
typedef __attribute__((ext_vector_type(4))) float f32x4;

__device__ __forceinline__ float wave_sum(float v) {
#pragma unroll
    for (int off = 32; off > 0; off >>= 1) v += __shfl_xor(v, off);
    return v;
}
__device__ __forceinline__ float wave_max(float v) {
#pragma unroll
    for (int off = 32; off > 0; off >>= 1) v = fmaxf(v, __shfl_xor(v, off));
    return v;
}
__device__ __forceinline__ float sigm(float x) { return 1.0f / (1.0f + expf(-x)); }
__device__ __forceinline__ ush f2bf(float f) {
    unsigned u = __float_as_uint(f);
    u += 0x7FFFu + ((u >> 16) & 1u);
    return (ush)(u >> 16);
}
__device__ __forceinline__ float bf2f(ush b) {
    return __uint_as_float(((unsigned)b) << 16);
}
__device__ __forceinline__ unsigned pack2(float a, float b) {
    return (unsigned)f2bf(a) | ((unsigned)f2bf(b) << 16);
}

// ---------------------------------------------------------------------------
// Fused weight conversion: 8 segments, one f4 per thread. Total 1253376 f4s.
struct ConvAllArgs {
    const float* src[8];
    ush* dst[8];
};
__global__ __launch_bounds__(256) void conv_all(ConvAllArgs a) {
    int i = blockIdx.x * 256 + threadIdx.x;
    int seg, base;
    if (i < 65536)        { seg = 0; base = 0; }
    else if (i < 131072)  { seg = 1; base = 65536; }
    else if (i < 262144)  { seg = 2; base = 131072; }
    else if (i < 270336)  { seg = 3; base = 262144; }
    else if (i < 663552)  { seg = 4; base = 270336; }
    else if (i < 860160)  { seg = 5; base = 663552; }
    else if (i < 1056768) { seg = 6; base = 860160; }
    else                  { seg = 7; base = 1056768; }
    int j = i - base;
    float4 v = ((const float4*)a.src[seg])[j];
    uint2 o;
    o.x = pack2(v.x, v.y);
    o.y = pack2(v.z, v.w);
    ((uint2*)a.dst[seg])[j] = o;
}

// fp32 -> bf16 convert (enc), 4 elems/thread
__global__ __launch_bounds__(256) void conv_kernel(const float* __restrict__ src,
                                                   ush* __restrict__ dst, int n4) {
    int i = blockIdx.x * 256 + threadIdx.x;
    if (i < n4) {
        float4 v = ((const float4*)src)[i];
        uint2 o;
        o.x = pack2(v.x, v.y);
        o.y = pack2(v.z, v.w);
        ((uint2*)dst)[i] = o;
    }
}

// gather embeddings -> bf16
__global__ __launch_bounds__(128) void gather_kernel(const float* __restrict__ embed_w,
                                                     const int* __restrict__ seq,
                                                     ush* __restrict__ xall) {
    int item = blockIdx.x;           // t*256 + m
    int t = item >> 8, m = item & 255;
    int row = seq[m * LL + t];
    float4 v = ((const float4*)(embed_w + (size_t)row * HH))[threadIdx.x];
    uint2 o;
    o.x = pack2(v.x, v.y);
    o.y = pack2(v.z, v.w);
    ((uint2*)(xall + (size_t)item * HH))[threadIdx.x] = o;
}

// ---------------------------------------------------------------------------
// Ws MFMA (proven in round 3): grid (128, 8), block 256.
__global__ __launch_bounds__(256) void ws_mfma(const float* __restrict__ enc,
                                               const ush* __restrict__ Wb,
                                               const float* __restrict__ bias,
                                               ush* __restrict__ Ws_bf) {
    int tid = threadIdx.x;
    int wave = tid >> 6, lane = tid & 63;
    int quad = lane >> 4, l16 = lane & 15;
    int m0 = blockIdx.x * 256 + wave * 64;
    int n0 = blockIdx.y * 64;
    int b = m0 >> 7;
    int s_base = m0 & 127;
    const float* eb = enc + (size_t)b * CC * SS;
    const ush* wp = Wb + (size_t)(n0 + l16) * 512 + quad * 8;
    f32x4 acc[4][4];
#pragma unroll
    for (int f = 0; f < 4; f++)
#pragma unroll
        for (int s = 0; s < 4; s++) acc[f][s] = (f32x4){0.f, 0.f, 0.f, 0.f};
    for (int k0 = 0; k0 < 512; k0 += 32) {
        short8 af[4], bfr[4];
#pragma unroll
        for (int f = 0; f < 4; f++) {
            int s = s_base + f * 16 + l16;
#pragma unroll
            for (int j = 0; j < 8; j++) {
                float v = eb[(size_t)(k0 + quad * 8 + j) * SS + s];
                af[f][j] = (short)f2bf(v);
            }
        }
#pragma unroll
        for (int s = 0; s < 4; s++)
            bfr[s] = *(const short8*)(wp + (size_t)s * 16 * 512 + k0);
#pragma unroll
        for (int f = 0; f < 4; f++)
#pragma unroll
            for (int s = 0; s < 4; s++)
                acc[f][s] = __builtin_amdgcn_mfma_f32_16x16x32_bf16(af[f], bfr[s], acc[f][s], 0, 0, 0);
    }
#pragma unroll
    for (int f = 0; f < 4; f++)
#pragma unroll
        for (int s = 0; s < 4; s++)
#pragma unroll
            for (int r = 0; r < 4; r++) {
                int m = m0 + f * 16 + quad * 4 + r;
                int n = n0 + s * 16 + l16;
                Ws_bf[(size_t)m * HH + n] = f2bf(acc[f][s][r] + bias[n]);
            }
}

// ---------------------------------------------------------------------------
// MFMA tile helpers
__device__ __forceinline__ void mfma_tile64(const ush* xp, const ush* wp, size_t wst,
                                            f32x4 acc[4]) {
    short8 a_c = *(const short8*)xp;
    short8 b0 = *(const short8*)(wp);
    short8 b1 = *(const short8*)(wp + 16 * wst);
    short8 b2 = *(const short8*)(wp + 32 * wst);
    short8 b3 = *(const short8*)(wp + 48 * wst);
#pragma unroll
    for (int ks = 0; ks < 16; ks++) {
        short8 a_n, c0, c1, c2, c3;
        if (ks < 15) {
            int k = (ks + 1) * 32;
            a_n = *(const short8*)(xp + k);
            c0 = *(const short8*)(wp + k);
            c1 = *(const short8*)(wp + 16 * wst + k);
            c2 = *(const short8*)(wp + 32 * wst + k);
            c3 = *(const short8*)(wp + 48 * wst + k);
        }
        acc[0] = __builtin_amdgcn_mfma_f32_16x16x32_bf16(a_c, b0, acc[0], 0, 0, 0);
        acc[1] = __builtin_amdgcn_mfma_f32_16x16x32_bf16(a_c, b1, acc[1], 0, 0, 0);
        acc[2] = __builtin_amdgcn_mfma_f32_16x16x32_bf16(a_c, b2, acc[2], 0, 0, 0);
        acc[3] = __builtin_amdgcn_mfma_f32_16x16x32_bf16(a_c, b3, acc[3], 0, 0, 0);
        if (ks < 15) { a_c = a_n; b0 = c0; b1 = c1; b2 = c2; b3 = c3; }
    }
}

__device__ __forceinline__ void mfma_tile16(const ush* xp, const ush* wp, f32x4& acc) {
#pragma unroll
    for (int ks = 0; ks < 16; ks++) {
        short8 a = *(const short8*)(xp + ks * 32);
        short8 b = *(const short8*)(wp + ks * 32);
        acc = __builtin_amdgcn_mfma_f32_16x16x32_bf16(a, b, acc, 0, 0, 0);
    }
}

// ---------------------------------------------------------------------------
// Phase device functions — shared by persistent (coop) path and fallback
// wrapper kernels. All grid-stride with (bid, nb).

__device__ __forceinline__ void phase_init(const float* __restrict__ is,
                                           float* __restrict__ h0, float* __restrict__ h1,
                                           ush* __restrict__ h0b, ush* __restrict__ h1b,
                                           float* __restrict__ acc, int gtid, int nthr) {
    for (int idx = gtid; idx < BB * HH; idx += nthr) {
        float a = is[idx & 511];
        float b = is[512 + (idx & 511)];
        h0[idx] = a; h1[idx] = b;
        h0b[idx] = f2bf(a); h1b[idx] = f2bf(b);
    }
    if (gtid < 2) acc[gtid] = 0.0f;
}

// Split-K GEMM phase writing P partials. Tile 64m x 64n per block-iter.
__device__ __forceinline__ void phase_gemmP(const ush* X0, const ush* X1, const ush* X2,
                                            const ush* W0, const ush* W1, const ush* W2,
                                            size_t wst01, size_t wst2, int nchunks,
                                            float* __restrict__ P,
                                            int bid, int nb, int wave, int quad, int l16) {
    int ntiles = nchunks * 96;
    for (int i = bid; i < ntiles; i += nb) {
        int z = i / 96, r = i - z * 96;
        int nh = r >> 2, mh = r & 3;
        const ush* X = (z == 0) ? X0 : ((z == 1) ? X1 : X2);
        const ush* W = (z == 0) ? W0 : ((z == 1) ? W1 : W2);
        size_t wst = (z == 2) ? wst2 : wst01;
        int m0 = mh * 64 + wave * 16, n0 = nh * 64;
        const ush* xp = X + (size_t)(m0 + l16) * 512 + quad * 8;
        const ush* wp = W + (size_t)(n0 + l16) * wst + quad * 8;
        f32x4 acc[4];
#pragma unroll
        for (int s = 0; s < 4; s++) acc[s] = (f32x4){0.f, 0.f, 0.f, 0.f};
        mfma_tile64(xp, wp, wst, acc);
        float* Pb = P + ((size_t)z * 256 + m0 + quad * 4) * 1536 + n0 + l16;
#pragma unroll
        for (int s = 0; s < 4; s++)
#pragma unroll
            for (int rr = 0; rr < 4; rr++) Pb[(size_t)rr * 1536 + s * 16] = acc[s][rr];
    }
}

__device__ __forceinline__ void phase_gate(const float* __restrict__ P, int za, int zb,
                                           const float* __restrict__ hp,
                                           const float* __restrict__ bih,
                                           const float* __restrict__ bhh,
                                           float* __restrict__ ho, ush* __restrict__ hob,
                                           int gtid, int nthr) {
    for (int e = gtid; e < 32768; e += nthr) {
        int m = e >> 7, n = (e & 127) * 4;
        float4 gi[3] = {}, gh[3] = {};
        for (int z = 0; z < za; z++) {
            const float* p = P + ((size_t)z * 256 + m) * 1536 + n;
#pragma unroll
            for (int g = 0; g < 3; g++) {
                float4 v = *(const float4*)(p + g * 512);
                gi[g].x += v.x; gi[g].y += v.y; gi[g].z += v.z; gi[g].w += v.w;
            }
        }
        for (int z = za; z < za + zb; z++) {
            const float* p = P + ((size_t)z * 256 + m) * 1536 + n;
#pragma unroll
            for (int g = 0; g < 3; g++) {
                float4 v = *(const float4*)(p + g * 512);
                gh[g].x += v.x; gh[g].y += v.y; gh[g].z += v.z; gh[g].w += v.w;
            }
        }
        float4 hv = *(const float4*)(hp + (size_t)m * 512 + n);
        float4 o;
        float* gi0 = (float*)&gi[0]; float* gi1 = (float*)&gi[1]; float* gi2 = (float*)&gi[2];
        float* gh0 = (float*)&gh[0]; float* gh1 = (float*)&gh[1]; float* gh2 = (float*)&gh[2];
        float* hvp = (float*)&hv; float* op = (float*)&o;
#pragma unroll
        for (int j = 0; j < 4; j++) {
            int nn = n + j;
            float r = sigm(gi0[j] + bih[nn] + gh0[j] + bhh[nn]);
            float zf = sigm(gi1[j] + bih[512 + nn] + gh1[j] + bhh[512 + nn]);
            float na = tanhf(gi2[j] + bih[1024 + nn] + r * (gh2[j] + bhh[1024 + nn]));
            op[j] = (1.0f - zf) * na + zf * hvp[j];
        }
        *(float4*)(ho + (size_t)m * 512 + n) = o;
        uint2 ob;
        ob.x = pack2(o.x, o.y);
        ob.y = pack2(o.z, o.w);
        *(uint2*)(hob + (size_t)m * 512 + n) = ob;
    }
}

__device__ __forceinline__ void phase_u(const ush* __restrict__ h_bf,
                                        const ush* __restrict__ wU,
                                        const float* __restrict__ Ub,
                                        float* __restrict__ u,
                                        int bid, int nb, int wave, int quad, int l16) {
    for (int i = bid; i < 128; i += nb) {
        int m0 = (i >> 3) * 16;
        int n0 = (i & 7) * 64 + wave * 16;
        const ush* xp = h_bf + (size_t)(m0 + l16) * 512 + quad * 8;
        const ush* wp = wU + (size_t)(n0 + l16) * 512 + quad * 8;
        f32x4 acc = (f32x4){0.f, 0.f, 0.f, 0.f};
        mfma_tile16(xp, wp, acc);
        int n = n0 + l16;
        float bia = Ub[n];
#pragma unroll
        for (int r = 0; r < 4; r++)
            u[(size_t)(m0 + quad * 4 + r) * 512 + n] = acc[r] + bia;
    }
}

__device__ __forceinline__ void phase_fc(const ush* __restrict__ ctx_bf,
                                         const ush* __restrict__ h_bf,
                                         const ush* __restrict__ wFc,
                                         const float* __restrict__ fcb,
                                         ush* __restrict__ y, ush* __restrict__ ys,
                                         int bid, int nb, int wave, int quad, int l16) {
    for (int i = bid; i < 128; i += nb) {
        int m0 = (i >> 3) * 16;
        int n0 = (i & 7) * 64 + wave * 16;
        const ush* wp = wFc + (size_t)(n0 + l16) * 1024 + quad * 8;
        const ush* xp = ctx_bf + (size_t)(m0 + l16) * 512 + quad * 8;
        f32x4 acc = (f32x4){0.f, 0.f, 0.f, 0.f};
        mfma_tile16(xp, wp, acc);
        xp = h_bf + (size_t)(m0 + l16) * 512 + quad * 8;
        mfma_tile16(xp, wp + 512, acc);
        int n = n0 + l16;
        float bia = fcb[n];
#pragma unroll
        for (int r = 0; r < 4; r++) {
            float v = fmaxf(acc[r] + bia, 0.0f);
            ush bv = f2bf(v);
            size_t off = (size_t)(m0 + quad * 4 + r) * 512 + n;
            y[off] = bv;
            if (ys) ys[off] = bv;
        }
    }
}

__device__ __forceinline__ void phase_attn(const float* __restrict__ u,
                                           const float* __restrict__ vw,
                                           const ush* __restrict__ Ws_bf,
                                           const ush* __restrict__ enc_bf,
                                           ush* __restrict__ ctx_bf,
                                           float* __restrict__ smem,
                                           int bid, int nb, int wave, int lane) {
    for (int b = bid; b < BB; b += nb) {
        int col = lane * 8;
        float4 u0 = *(const float4*)(u + (size_t)b * 512 + col);
        float4 u0b = *(const float4*)(u + (size_t)b * 512 + col + 4);
        float ur[8] = {u0.x, u0.y, u0.z, u0.w, u0b.x, u0b.y, u0b.z, u0b.w};
        float4 v0 = *(const float4*)(vw + col);
        float4 v1 = *(const float4*)(vw + col + 4);
        float vr[8] = {v0.x, v0.y, v0.z, v0.w, v1.x, v1.y, v1.z, v1.w};
        const ush* wsb = Ws_bf + (size_t)b * SS * HH;
#pragma unroll
        for (int gg = 0; gg < 4; gg++) {
            int s0 = wave * 32 + gg * 8;
            float p[8];
#pragma unroll
            for (int j = 0; j < 8; j++) {
                short8 rv = *(const short8*)(wsb + (size_t)(s0 + j) * HH + col);
                float acc = 0.0f;
#pragma unroll
                for (int q = 0; q < 8; q++) {
                    float e = bf2f((ush)rv[q]) + ur[q];
                    acc += fmaxf(e, 0.0f) * vr[q];
                }
                p[j] = acc;
            }
#pragma unroll
            for (int off = 32; off > 0; off >>= 1)
#pragma unroll
                for (int j = 0; j < 8; j++) p[j] += __shfl_xor(p[j], off);
            float out = p[0];
#pragma unroll
            for (int j = 1; j < 8; j++)
                if (lane == j) out = p[j];
            if (lane < 8) smem[s0 + lane] = out;
        }
        __syncthreads();
        if (wave == 0) {
            float s0v = smem[lane], s1v = smem[lane + 64];
            float m = wave_max(fmaxf(s0v, s1v));
            float e0 = expf(s0v - m), e1 = expf(s1v - m);
            float ssum = wave_sum(e0 + e1);
            float inv = 1.0f / ssum;
            smem[lane] = e0 * inv;
            smem[lane + 64] = e1 * inv;
        }
        __syncthreads();
        float ax = smem[lane * 2], ay = smem[lane * 2 + 1];
        const ush* eb = enc_bf + (size_t)b * CC * SS;
#pragma unroll
        for (int g = 0; g < 16; g++) {
            float p[8];
#pragma unroll
            for (int j = 0; j < 8; j++) {
                int c = wave * 128 + g * 8 + j;
                unsigned ev = *(const unsigned*)(eb + (size_t)c * SS + lane * 2);
                float flo = __uint_as_float(ev << 16);
                float fhi = __uint_as_float(ev & 0xFFFF0000u);
                p[j] = flo * ax + fhi * ay;
            }
#pragma unroll
            for (int off = 32; off > 0; off >>= 1)
#pragma unroll
                for (int j = 0; j < 8; j++) p[j] += __shfl_xor(p[j], off);
            float out = p[0];
#pragma unroll
            for (int j = 1; j < 8; j++)
                if (lane == j) out = p[j];
            if (lane < 8) ctx_bf[(size_t)b * CC + wave * 128 + g * 8 + lane] = f2bf(out);
        }
        __syncthreads();
    }
}

__device__ __forceinline__ void phase_cls(const ush* __restrict__ ys_bf,
                                          const ush* __restrict__ wCls,
                                          float* __restrict__ logits,
                                          int bid, int nb, int wave, int quad, int l16) {
    for (int i = bid; i < 92; i += nb) {
        int m0 = i * 64 + wave * 16;
        const ush* xp = ys_bf + (size_t)(m0 + l16) * 512 + quad * 8;
        const ush* wp = wCls + (size_t)l16 * 512 + quad * 8;
        f32x4 acc4[4];
#pragma unroll
        for (int s = 0; s < 4; s++) acc4[s] = (f32x4){0.f, 0.f, 0.f, 0.f};
        mfma_tile64(xp, wp, 512, acc4);
        float* Lb = logits + (size_t)(m0 + quad * 4) * 64 + l16;
#pragma unroll
        for (int s = 0; s < 4; s++)
#pragma unroll
            for (int rr = 0; rr < 4; rr++) Lb[(size_t)rr * 64 + s * 16] = acc4[s][rr];
    }
}

__device__ __forceinline__ void phase_nll(const float* __restrict__ logits,
                                          const float* __restrict__ cls_b,
                                          const int* __restrict__ seq,
                                          float* __restrict__ acc,
                                          int bid, int nb, int wave, int lane) {
    float biasv = cls_b[lane];
    float lsum = 0.0f, lcnt = 0.0f;
    for (int item = bid * 4 + wave; item < 5888; item += nb * 4) {
        int t = item >> 8, b = item & 255;
        float v = logits[(size_t)item * 64 + lane] + biasv;
        float m = wave_max(v);
        float e = expf(v - m);
        float s = wave_sum(e);
        int label = seq[b * LL + t + 1];
        float vl = __shfl(v, label);
        if (lane == 0 && label > 0) {
            lsum += -(vl - m - logf(s));
            lcnt += 1.0f;
        }
    }
    if (lane == 0 && (lsum != 0.0f || lcnt != 0.0f)) {
        atomicAdd(&acc[0], lsum);
        atomicAdd(&acc[1], lcnt);
    }
}

// ---------------------------------------------------------------------------
struct PArgs {
    const float* init_state;
    const int* seq;
    const float* attn_U_b;
    const float* attn_v_w;
    const float* fc_b;
    const float* g0_bih; const float* g0_bhh;
    const float* g1_bih; const float* g1_bhh;
    const float* cls_b;
    const ush* Ws_bf; const ush* enc_bf; const ush* xall_bf;
    const ush* wU; const ush* wFc;
    const ush* wG0i; const ush* wG0h; const ush* wG1i; const ush* wG1h;
    const ush* wCls;
    float* P; float* u; float* logits; float* acc;
    float* h0a; float* h0b; float* h1a; float* h1b;
    ush* h0a_bf; ush* h0b_bf; ush* h1a_bf; ush* h1b_bf;
    ush* y_bf; ush* ctx_bf; ush* ys_bf;
    float* out;
};

// ---------------------------------------------------------------------------
// Persistent cooperative kernel (path A)
__global__ __launch_bounds__(256) void persist_kernel(PArgs A) {
    cg::grid_group grid = cg::this_grid();
    int nb = gridDim.x;
    int tid = threadIdx.x, bid = blockIdx.x;
    int wave = tid >> 6, lane = tid & 63;
    int quad = lane >> 4, l16 = lane & 15;
    int gtid = bid * 256 + tid;
    int nthr = nb * 256;
    __shared__ float smem[SS];

    phase_init(A.init_state, A.h0a, A.h1a, A.h0a_bf, A.h1a_bf, A.acc, gtid, nthr);
    grid.sync();

    float* h0_in = A.h0a; float* h0_out = A.h0b;
    float* h1_in = A.h1a; float* h1_out = A.h1b;
    ush* h0_in_bf = A.h0a_bf; ush* h0_out_bf = A.h0b_bf;
    ush* h1_in_bf = A.h1a_bf; ush* h1_out_bf = A.h1b_bf;

    // prologue: y0 = out_proj(attn(h1), h1)
    phase_u(h1_in_bf, A.wU, A.attn_U_b, A.u, bid, nb, wave, quad, l16);
    grid.sync();
    phase_attn(A.u, A.attn_v_w, A.Ws_bf, A.enc_bf, A.ctx_bf, smem, bid, nb, wave, lane);
    grid.sync();
    phase_fc(A.ctx_bf, h1_in_bf, A.wFc, A.fc_b, A.y_bf, nullptr, bid, nb, wave, quad, l16);
    grid.sync();

    for (int t = 0; t < LL - 1; t++) {
        phase_gemmP(A.y_bf, A.xall_bf + (size_t)t * BB * HH, h0_in_bf,
                    A.wG0i, A.wG0i + 512, A.wG0h, 1024, 512, 3, A.P,
                    bid, nb, wave, quad, l16);
        grid.sync();
        phase_gate(A.P, 2, 1, h0_in, A.g0_bih, A.g0_bhh, h0_out, h0_out_bf, gtid, nthr);
        grid.sync();
        phase_gemmP(h0_out_bf, h1_in_bf, nullptr,
                    A.wG1i, A.wG1h, nullptr, 512, 512, 2, A.P,
                    bid, nb, wave, quad, l16);
        grid.sync();
        phase_gate(A.P, 1, 1, h1_in, A.g1_bih, A.g1_bhh, h1_out, h1_out_bf, gtid, nthr);
        grid.sync();
        phase_u(h1_out_bf, A.wU, A.attn_U_b, A.u, bid, nb, wave, quad, l16);
        grid.sync();
        phase_attn(A.u, A.attn_v_w, A.Ws_bf, A.enc_bf, A.ctx_bf, smem, bid, nb, wave, lane);
        grid.sync();
        phase_fc(A.ctx_bf, h1_out_bf, A.wFc, A.fc_b, A.y_bf,
                 A.ys_bf + (size_t)t * BB * HH, bid, nb, wave, quad, l16);
        grid.sync();
        float* tf;
        tf = h0_in; h0_in = h0_out; h0_out = tf;
        tf = h1_in; h1_in = h1_out; h1_out = tf;
        ush* tb;
        tb = h0_in_bf; h0_in_bf = h0_out_bf; h0_out_bf = tb;
        tb = h1_in_bf; h1_in_bf = h1_out_bf; h1_out_bf = tb;
    }

    phase_cls(A.ys_bf, A.wCls, A.logits, bid, nb, wave, quad, l16);
    grid.sync();
    phase_nll(A.logits, A.cls_b, A.seq, A.acc, bid, nb, wave, lane);
    grid.sync();
    if (gtid == 0) A.out[0] = A.acc[0] / A.acc[1];
}

// ---------------------------------------------------------------------------
// Fallback wrapper kernels (path B) — same phases, kernel-boundary sync.
__global__ __launch_bounds__(256) void w_init(const float* is, float* h0, float* h1,
                                              ush* h0b, ush* h1b, float* acc) {
    phase_init(is, h0, h1, h0b, h1b, acc,
               blockIdx.x * 256 + threadIdx.x, gridDim.x * 256);
}
__global__ __launch_bounds__(256) void w_gemmP(const ush* X0, const ush* X1, const ush* X2,
                                               const ush* W0, const ush* W1, const ush* W2,
                                               int wst01, int wst2, int nchunks, float* P) {
    int tid = threadIdx.x;
    int wave = tid >> 6, lane = tid & 63;
    phase_gemmP(X0, X1, X2, W0, W1, W2, wst01, wst2, nchunks, P,
                blockIdx.x, gridDim.x, wave, lane >> 4, lane & 15);
}
__global__ __launch_bounds__(256) void w_gate(const float* P, int za, int zb,
                                              const float* hp, const float* bih,
                                              const float* bhh, float* ho, ush* hob) {
    phase_gate(P, za, zb, hp, bih, bhh, ho, hob,
               blockIdx.x * 256 + threadIdx.x, gridDim.x * 256);
}
__global__ __launch_bounds__(256) void w_u(const ush* h_bf, const ush* wU,
                                           const float* Ub, float* u) {
    int tid = threadIdx.x;
    int wave = tid >> 6, lane = tid & 63;
    phase_u(h_bf, wU, Ub, u, blockIdx.x, gridDim.x, wave, lane >> 4, lane & 15);
}
__global__ __launch_bounds__(256) void w_attn(const float* u, const float* vw,
                                              const ush* Ws_bf, const ush* enc_bf,
                                              ush* ctx_bf) {
    __shared__ float smem[SS];
    int tid = threadIdx.x;
    phase_attn(u, vw, Ws_bf, enc_bf, ctx_bf, smem, blockIdx.x, gridDim.x,
               tid >> 6, tid & 63);
}
__global__ __launch_bounds__(256) void w_fc(const ush* ctx_bf, const ush* h_bf,
                                            const ush* wFc, const float* fcb,
                                            ush* y, ush* ys) {
    int tid = threadIdx.x;
    int wave = tid >> 6, lane = tid & 63;
    phase_fc(ctx_bf, h_bf, wFc, fcb, y, ys, blockIdx.x, gridDim.x,
             wave, lane >> 4, lane & 15);
}
__global__ __launch_bounds__(256) void w_cls(const ush* ys_bf, const ush* wCls,
                                             float* logits) {
    int tid = threadIdx.x;
    int wave = tid >> 6, lane = tid & 63;
    phase_cls(ys_bf, wCls, logits, blockIdx.x, gridDim.x, wave, lane >> 4, lane & 15);
}
__global__ __launch_bounds__(256) void w_nll(const float* logits, const float* cls_b,
                                             const int* seq, float* acc) {
    int tid = threadIdx.x;
    phase_nll(logits, cls_b, seq, acc, blockIdx.x, gridDim.x, tid >> 6, tid & 63);
}
__global__ void w_final(const float* acc, float* out) {
    if (threadIdx.x == 0) out[0] = acc[0] / acc[1];
}

// ---------------------------------------------------------------------------
extern "C" void kernel_launch(void* const* d_in, const int* in_sizes, int n_in,
                              void* d_out, int out_size, void* d_ws, size_t ws_size,
                              hipStream_t stream) {
    const float* enc        = (const float*)d_in[0];
    const int*   seq        = (const int*)d_in[1];
    const float* embed_w    = (const float*)d_in[3];
    const float* init_state = (const float*)d_in[4];
    const float* attn_W_w   = (const float*)d_in[5];
    const float* attn_W_b   = (const float*)d_in[6];
    const float* attn_U_w   = (const float*)d_in[7];
    const float* attn_U_b   = (const float*)d_in[8];
    const float* attn_v_w   = (const float*)d_in[9];
    const float* fc_w       = (const float*)d_in[11];
    const float* fc_b       = (const float*)d_in[12];
    const float* cls_w      = (const float*)d_in[13];
    const float* cls_b      = (const float*)d_in[14];
    const float* g0_wih     = (const float*)d_in[15];
    const float* g0_whh     = (const float*)d_in[16];
    const float* g0_bih     = (const float*)d_in[17];
    const float* g0_bhh     = (const float*)d_in[18];
    const float* g1_wih     = (const float*)d_in[19];
    const float* g1_whh     = (const float*)d_in[20];
    const float* g1_bih     = (const float*)d_in[21];
    const float* g1_bhh     = (const float*)d_in[22];
    float* out = (float*)d_out;

    float* ws = (float*)d_ws;
    size_t o = 0;
    ush* Ws_bf   = (ush*)(ws + o); o += (size_t)BB * SS * HH / 2;
    ush* enc_bf  = (ush*)(ws + o); o += (size_t)BB * CC * SS / 2;
    ush* ys_bf   = (ush*)(ws + o); o += (size_t)(LL - 1) * BB * HH / 2;
    ush* xall_bf = (ush*)(ws + o); o += (size_t)(LL - 1) * BB * HH / 2;
    ush* wWb  = (ush*)(ws + o); o += 262144 / 2;
    ush* wU   = (ush*)(ws + o); o += 262144 / 2;
    ush* wFc  = (ush*)(ws + o); o += 524288 / 2;
    ush* wCls = (ush*)(ws + o); o += 32768 / 2;
    ush* wG0i = (ush*)(ws + o); o += 1572864 / 2;
    ush* wG0h = (ush*)(ws + o); o += 786432 / 2;
    ush* wG1i = (ush*)(ws + o); o += 786432 / 2;
    ush* wG1h = (ush*)(ws + o); o += 786432 / 2;
    float* P      = ws + o; o += (size_t)3 * BB * 1536;
    float* u      = ws + o; o += (size_t)BB * HH;
    float* logits = ws + o; o += (size_t)(LL - 1) * BB * VV;
    float* h0a    = ws + o; o += (size_t)BB * HH;
    float* h0b    = ws + o; o += (size_t)BB * HH;
    float* h1a    = ws + o; o += (size_t)BB * HH;
    float* h1b    = ws + o; o += (size_t)BB * HH;
    float* accb   = ws + o; o += 256;
    ush* h0a_bf = (ush*)(ws + o); o += (size_t)BB * HH / 2;
    ush* h0b_bf = (ush*)(ws + o); o += (size_t)BB * HH / 2;
    ush* h1a_bf = (ush*)(ws + o); o += (size_t)BB * HH / 2;
    ush* h1b_bf = (ush*)(ws + o); o += (size_t)BB * HH / 2;
    ush* y_bf   = (ush*)(ws + o); o += (size_t)BB * HH / 2;
    ush* ctx_bf = (ush*)(ws + o); o += (size_t)BB * CC / 2;

    // Common prologue (normal launches)
    ConvAllArgs ca;
    ca.src[0] = attn_W_w; ca.dst[0] = wWb;
    ca.src[1] = attn_U_w; ca.dst[1] = wU;
    ca.src[2] = fc_w;     ca.dst[2] = wFc;
    ca.src[3] = cls_w;    ca.dst[3] = wCls;
    ca.src[4] = g0_wih;   ca.dst[4] = wG0i;
    ca.src[5] = g0_whh;   ca.dst[5] = wG0h;
    ca.src[6] = g1_wih;   ca.dst[6] = wG1i;
    ca.src[7] = g1_whh;   ca.dst[7] = wG1h;
    conv_all<<<4896, 256, 0, stream>>>(ca);
    conv_kernel<<<16384, 256, 0, stream>>>(enc, enc_bf, 4194304);
    gather_kernel<<<(LL - 1) * BB, 128, 0, stream>>>(embed_w, seq, xall_bf);
    ws_mfma<<<dim3(128, 8), 256, 0, stream>>>(enc, wWb, attn_W_b, Ws_bf);

    PArgs pa;
    pa.init_state = init_state; pa.seq = seq;
    pa.attn_U_b = attn_U_b; pa.attn_v_w = attn_v_w; pa.fc_b = fc_b;
    pa.g0_bih = g0_bih; pa.g0_bhh = g0_bhh;
    pa.g1_bih = g1_bih; pa.g1_bhh = g1_bhh;
    pa.cls_b = cls_b;
    pa.Ws_bf = Ws_bf; pa.enc_bf = enc_bf; pa.xall_bf = xall_bf;
    pa.wU = wU; pa.wFc = wFc;
    pa.wG0i = wG0i; pa.wG0h = wG0h; pa.wG1i = wG1i; pa.wG1h = wG1h;
    pa.wCls = wCls;
    pa.P = P; pa.u = u; pa.logits = logits; pa.acc = accb;
    pa.h0a = h0a; pa.h0b = h0b; pa.h1a = h1a; pa.h1b = h1b;
    pa.h0a_bf = h0a_bf; pa.h0b_bf = h0b_bf; pa.h1a_bf = h1a_bf; pa.h1b_bf = h1b_bf;
    pa.y_bf = y_bf; pa.ctx_bf = ctx_bf; pa.ys_bf = ys_bf;
    pa.out = out;

    // Path A: cooperative persistent kernel (check the return code!)
    void* kargs[] = { (void*)&pa };
    hipError_t cerr = hipLaunchCooperativeKernel((const void*)persist_kernel,
                                                 dim3(256), dim3(256), kargs, 0, stream);
    if (cerr != hipSuccess)
        cerr = hipLaunchCooperativeKernel((const void*)persist_kernel,
                                          dim3(128), dim3(256), kargs, 0, stream);
    if (cerr == hipSuccess) return;

    // Path B: fallback — identical phases as separate launches.
    w_init<<<512, 256, 0, stream>>>(init_state, h0a, h1a, h0a_bf, h1a_bf, accb);

    float* h0_in = h0a; float* h0_out = h0b;
    float* h1_in = h1a; float* h1_out = h1b;
    ush* h0_in_bf = h0a_bf; ush* h0_out_bf = h0b_bf;
    ush* h1_in_bf = h1a_bf; ush* h1_out_bf = h1b_bf;

    w_u<<<128, 256, 0, stream>>>(h1_in_bf, wU, attn_U_b, u);
    w_attn<<<256, 256, 0, stream>>>(u, attn_v_w, Ws_bf, enc_bf, ctx_bf);
    w_fc<<<128, 256, 0, stream>>>(ctx_bf, h1_in_bf, wFc, fc_b, y_bf, nullptr);

    for (int t = 0; t < LL - 1; t++) {
        w_gemmP<<<288, 256, 0, stream>>>(y_bf, xall_bf + (size_t)t * BB * HH, h0_in_bf,
                                         wG0i, wG0i + 512, wG0h, 1024, 512, 3, P);
        w_gate<<<128, 256, 0, stream>>>(P, 2, 1, h0_in, g0_bih, g0_bhh, h0_out, h0_out_bf);
        w_gemmP<<<192, 256, 0, stream>>>(h0_out_bf, h1_in_bf, nullptr,
                                         wG1i, wG1h, nullptr, 512, 512, 2, P);
        w_gate<<<128, 256, 0, stream>>>(P, 1, 1, h1_in, g1_bih, g1_bhh, h1_out, h1_out_bf);
        w_u<<<128, 256, 0, stream>>>(h1_out_bf, wU, attn_U_b, u);
        w_attn<<<256, 256, 0, stream>>>(u, attn_v_w, Ws_bf, enc_bf, ctx_bf);
        w_fc<<<128, 256, 0, stream>>>(ctx_bf, h1_out_bf, wFc, fc_b, y_bf,
                                      ys_bf + (size_t)t * BB * HH);
        float* tf;
        tf = h0_in; h0_in = h0_out; h0_out = tf;
        tf = h1_in; h1_in = h1_out; h1_out = tf;
        ush* tb;
        tb = h0_in_bf; h0_in_bf = h0_out_bf; h0_out_bf = tb;
        tb = h1_in_bf; h1_in_bf = h1_out_bf; h1_out_bf = tb;
    }

    w_cls<<<92, 256, 0, stream>>>(ys_bf, wCls, logits);
    w_nll<<<256, 256, 0, stream>>>(logits, cls_b, seq, accb);
    w_final<<<1, 64, 0, stream>>>(accb, out);
}

// Round 6
// 2474.373 us; speedup vs baseline: 2.6387x; 2.6387x over previous
//
#include <hip/hip_runtime.h>
#include <hip/hip_bf16.h>
#include <cstddef>

// Problem dims (fixed)
#define BB 256
#define CC 512
#define SS 128      // FH*FW = 8*16
#define HH 512
#define VV 64
#define LL 24       // sequence length; steps = 23

typedef unsigned short ush;
typedef __attribute__((ext_vector_type(8))) short short8;
typedef __attribute__((ext_vector_type(4))) float f32x4;

__device__ __forceinline__ float wave_sum(float v) {
#pragma unroll
    for (int off = 32; off > 0; off >>= 1) v += __shfl_xor(v, off);
    return v;
}
__device__ __forceinline__ float wave_max(float v) {
#pragma unroll
    for (int off = 32; off > 0; off >>= 1) v = fmaxf(v, __shfl_xor(v, off));
    return v;
}
__device__ __forceinline__ float sigm(float x) { return 1.0f / (1.0f + expf(-x)); }
__device__ __forceinline__ ush f2bf(float f) {
    unsigned u = __float_as_uint(f);
    u += 0x7FFFu + ((u >> 16) & 1u);
    return (ush)(u >> 16);
}
__device__ __forceinline__ float bf2f(ush b) {
    return __uint_as_float(((unsigned)b) << 16);
}
__device__ __forceinline__ unsigned pack2(float a, float b) {
    return (unsigned)f2bf(a) | ((unsigned)f2bf(b) << 16);
}

// ---------------------------------------------------------------------------
// Fused weight conversion: 8 segments, one f4 per thread. Total 1253376 f4s.
struct ConvAllArgs {
    const float* src[8];
    ush* dst[8];
};
__global__ __launch_bounds__(256) void conv_all(ConvAllArgs a) {
    int i = blockIdx.x * 256 + threadIdx.x;
    int seg, base;
    if (i < 65536)        { seg = 0; base = 0; }
    else if (i < 131072)  { seg = 1; base = 65536; }
    else if (i < 262144)  { seg = 2; base = 131072; }
    else if (i < 270336)  { seg = 3; base = 262144; }
    else if (i < 663552)  { seg = 4; base = 270336; }
    else if (i < 860160)  { seg = 5; base = 663552; }
    else if (i < 1056768) { seg = 6; base = 860160; }
    else                  { seg = 7; base = 1056768; }
    int j = i - base;
    float4 v = ((const float4*)a.src[seg])[j];
    uint2 o;
    o.x = pack2(v.x, v.y);
    o.y = pack2(v.z, v.w);
    ((uint2*)a.dst[seg])[j] = o;
}

// fp32 -> bf16 convert (enc), 4 elems/thread
__global__ __launch_bounds__(256) void conv_kernel(const float* __restrict__ src,
                                                   ush* __restrict__ dst, int n4) {
    int i = blockIdx.x * 256 + threadIdx.x;
    if (i < n4) {
        float4 v = ((const float4*)src)[i];
        uint2 o;
        o.x = pack2(v.x, v.y);
        o.y = pack2(v.z, v.w);
        ((uint2*)dst)[i] = o;
    }
}

// gather embeddings -> bf16
__global__ __launch_bounds__(128) void gather_kernel(const float* __restrict__ embed_w,
                                                     const int* __restrict__ seq,
                                                     ush* __restrict__ xall) {
    int item = blockIdx.x;           // t*256 + m
    int t = item >> 8, m = item & 255;
    int row = seq[m * LL + t];
    float4 v = ((const float4*)(embed_w + (size_t)row * HH))[threadIdx.x];
    uint2 o;
    o.x = pack2(v.x, v.y);
    o.y = pack2(v.z, v.w);
    ((uint2*)(xall + (size_t)item * HH))[threadIdx.x] = o;
}

// init: h states fp32+bf16, zero acc
__global__ __launch_bounds__(256) void init_kernel(const float* __restrict__ is,
                                                   float* __restrict__ h0,
                                                   float* __restrict__ h1,
                                                   ush* __restrict__ h0b,
                                                   ush* __restrict__ h1b,
                                                   float* __restrict__ acc) {
    int idx = blockIdx.x * 256 + threadIdx.x;
    if (idx < BB * HH) {
        float a = is[idx & 511];
        float b = is[512 + (idx & 511)];
        h0[idx] = a; h1[idx] = b;
        h0b[idx] = f2bf(a); h1b[idx] = f2bf(b);
    }
    if (idx < 2) acc[idx] = 0.0f;
}

// ---------------------------------------------------------------------------
// MFMA tile helpers (layouts proven in R3: A row=l16 k=quad*8+j; B row=l16 same;
// D col=l16 row=quad*4+r)
__device__ __forceinline__ void mfma_tile64(const ush* xp, const ush* wp, size_t wst,
                                            f32x4 acc[4]) {
    short8 a_c = *(const short8*)xp;
    short8 b0 = *(const short8*)(wp);
    short8 b1 = *(const short8*)(wp + 16 * wst);
    short8 b2 = *(const short8*)(wp + 32 * wst);
    short8 b3 = *(const short8*)(wp + 48 * wst);
#pragma unroll
    for (int ks = 0; ks < 16; ks++) {
        short8 a_n, c0, c1, c2, c3;
        if (ks < 15) {
            int k = (ks + 1) * 32;
            a_n = *(const short8*)(xp + k);
            c0 = *(const short8*)(wp + k);
            c1 = *(const short8*)(wp + 16 * wst + k);
            c2 = *(const short8*)(wp + 32 * wst + k);
            c3 = *(const short8*)(wp + 48 * wst + k);
        }
        acc[0] = __builtin_amdgcn_mfma_f32_16x16x32_bf16(a_c, b0, acc[0], 0, 0, 0);
        acc[1] = __builtin_amdgcn_mfma_f32_16x16x32_bf16(a_c, b1, acc[1], 0, 0, 0);
        acc[2] = __builtin_amdgcn_mfma_f32_16x16x32_bf16(a_c, b2, acc[2], 0, 0, 0);
        acc[3] = __builtin_amdgcn_mfma_f32_16x16x32_bf16(a_c, b3, acc[3], 0, 0, 0);
        if (ks < 15) { a_c = a_n; b0 = c0; b1 = c1; b2 = c2; b3 = c3; }
    }
}

__device__ __forceinline__ void mfma_tile16(const ush* xp, const ush* wp, f32x4& acc) {
#pragma unroll
    for (int ks = 0; ks < 16; ks++) {
        short8 a = *(const short8*)(xp + ks * 32);
        short8 b = *(const short8*)(wp + ks * 32);
        acc = __builtin_amdgcn_mfma_f32_16x16x32_bf16(a, b, acc, 0, 0, 0);
    }
}

// ---------------------------------------------------------------------------
// Ws MFMA (proven R3): grid (128, 8), block 256. Out bf16.
__global__ __launch_bounds__(256) void ws_mfma(const float* __restrict__ enc,
                                               const ush* __restrict__ Wb,
                                               const float* __restrict__ bias,
                                               ush* __restrict__ Ws_bf) {
    int tid = threadIdx.x;
    int wave = tid >> 6, lane = tid & 63;
    int quad = lane >> 4, l16 = lane & 15;
    int m0 = blockIdx.x * 256 + wave * 64;
    int n0 = blockIdx.y * 64;
    int b = m0 >> 7;
    int s_base = m0 & 127;
    const float* eb = enc + (size_t)b * CC * SS;
    const ush* wp = Wb + (size_t)(n0 + l16) * 512 + quad * 8;
    f32x4 acc[4][4];
#pragma unroll
    for (int f = 0; f < 4; f++)
#pragma unroll
        for (int s = 0; s < 4; s++) acc[f][s] = (f32x4){0.f, 0.f, 0.f, 0.f};
    for (int k0 = 0; k0 < 512; k0 += 32) {
        short8 af[4], bfr[4];
#pragma unroll
        for (int f = 0; f < 4; f++) {
            int s = s_base + f * 16 + l16;
#pragma unroll
            for (int j = 0; j < 8; j++) {
                float v = eb[(size_t)(k0 + quad * 8 + j) * SS + s];
                af[f][j] = (short)f2bf(v);
            }
        }
#pragma unroll
        for (int s = 0; s < 4; s++)
            bfr[s] = *(const short8*)(wp + (size_t)s * 16 * 512 + k0);
#pragma unroll
        for (int f = 0; f < 4; f++)
#pragma unroll
            for (int s = 0; s < 4; s++)
                acc[f][s] = __builtin_amdgcn_mfma_f32_16x16x32_bf16(af[f], bfr[s], acc[f][s], 0, 0, 0);
    }
#pragma unroll
    for (int f = 0; f < 4; f++)
#pragma unroll
        for (int s = 0; s < 4; s++)
#pragma unroll
            for (int r = 0; r < 4; r++) {
                int m = m0 + f * 16 + quad * 4 + r;
                int n = n0 + s * 16 + l16;
                Ws_bf[(size_t)m * HH + n] = f2bf(acc[f][s][r] + bias[n]);
            }
}

// ---------------------------------------------------------------------------
// Gx precompute: Gx[m, c] = xall[m,:] @ wG0i[c, 512:1024].T  (bf16 out)
// M=5888, N=1536, K=512. grid (92, 24), block 256 (4 waves x 16m).
__global__ __launch_bounds__(256) void gx_mfma(const ush* __restrict__ xall,
                                               const ush* __restrict__ wG0i,
                                               ush* __restrict__ Gx) {
    int tid = threadIdx.x;
    int wave = tid >> 6, lane = tid & 63;
    int quad = lane >> 4, l16 = lane & 15;
    int m0 = blockIdx.x * 64 + wave * 16;
    int n0 = blockIdx.y * 64;
    const ush* xp = xall + (size_t)(m0 + l16) * 512 + quad * 8;
    const ush* wp = wG0i + (size_t)(n0 + l16) * 1024 + 512 + quad * 8;
    f32x4 acc[4];
#pragma unroll
    for (int s = 0; s < 4; s++) acc[s] = (f32x4){0.f, 0.f, 0.f, 0.f};
    mfma_tile64(xp, wp, 1024, acc);
#pragma unroll
    for (int s = 0; s < 4; s++)
#pragma unroll
        for (int rr = 0; rr < 4; rr++)
            Gx[(size_t)(m0 + quad * 4 + rr) * 1536 + n0 + s * 16 + l16] = f2bf(acc[s][rr]);
}

// ---------------------------------------------------------------------------
// Fused GRU: GEMM (no split-K) + gate epilogue. Tile 32m x 32n, grid 128,
// block 256 = 4 waves as 2x2 (wm, wn). Accs: r (xa.Wi_r + xb.Wh_r), z, gi_n, gh_n.
// HASGX: add precomputed x-part (Gx) in epilogue (gru0).
template <bool HASGX, int WSTI>
__global__ __launch_bounds__(256) void gru_fused(const ush* __restrict__ xa,
                                                 const ush* __restrict__ xb,
                                                 const ush* __restrict__ wi,
                                                 const ush* __restrict__ wh,
                                                 const ush* __restrict__ Gx_t,
                                                 const float* __restrict__ bih,
                                                 const float* __restrict__ bhh,
                                                 const float* __restrict__ h_prev,
                                                 float* __restrict__ h_out,
                                                 ush* __restrict__ h_out_bf) {
    int tid = threadIdx.x;
    int wave = tid >> 6, lane = tid & 63;
    int quad = lane >> 4, l16 = lane & 15;
    int mt = blockIdx.x >> 4, nh = blockIdx.x & 15;
    int wm = wave >> 1, wn = wave & 1;
    int m0 = mt * 32 + wm * 16;
    int nrow = nh * 32 + wn * 16 + l16;           // 0..511
    const ush* xp_a = xa + (size_t)(m0 + l16) * 512 + quad * 8;
    const ush* xp_b = xb + (size_t)(m0 + l16) * 512 + quad * 8;
    const ush* wr = wi + (size_t)nrow * WSTI + quad * 8;
    const ush* wz = wi + (size_t)(512 + nrow) * WSTI + quad * 8;
    const ush* wnn = wi + (size_t)(1024 + nrow) * WSTI + quad * 8;
    const ush* hr = wh + (size_t)nrow * 512 + quad * 8;
    const ush* hz = wh + (size_t)(512 + nrow) * 512 + quad * 8;
    const ush* hn = wh + (size_t)(1024 + nrow) * 512 + quad * 8;
    f32x4 ar = (f32x4){0.f, 0.f, 0.f, 0.f};
    f32x4 az = ar, ain = ar, ahn = ar;
#pragma unroll
    for (int ks = 0; ks < 16; ks++) {
        short8 a = *(const short8*)(xp_a + ks * 32);
        ar  = __builtin_amdgcn_mfma_f32_16x16x32_bf16(a, *(const short8*)(wr + ks * 32), ar, 0, 0, 0);
        az  = __builtin_amdgcn_mfma_f32_16x16x32_bf16(a, *(const short8*)(wz + ks * 32), az, 0, 0, 0);
        ain = __builtin_amdgcn_mfma_f32_16x16x32_bf16(a, *(const short8*)(wnn + ks * 32), ain, 0, 0, 0);
    }
#pragma unroll
    for (int ks = 0; ks < 16; ks++) {
        short8 a = *(const short8*)(xp_b + ks * 32);
        ar  = __builtin_amdgcn_mfma_f32_16x16x32_bf16(a, *(const short8*)(hr + ks * 32), ar, 0, 0, 0);
        az  = __builtin_amdgcn_mfma_f32_16x16x32_bf16(a, *(const short8*)(hz + ks * 32), az, 0, 0, 0);
        ahn = __builtin_amdgcn_mfma_f32_16x16x32_bf16(a, *(const short8*)(hn + ks * 32), ahn, 0, 0, 0);
    }
    int n = nrow;
    float br = bih[n] + bhh[n];
    float bz = bih[512 + n] + bhh[512 + n];
    float bin = bih[1024 + n];
    float bhn = bhh[1024 + n];
#pragma unroll
    for (int rr = 0; rr < 4; rr++) {
        int m = m0 + quad * 4 + rr;
        float gr = ar[rr], gz = az[rr], gin = ain[rr];
        if (HASGX) {
            const ush* gx = Gx_t + (size_t)m * 1536;
            gr += bf2f(gx[n]);
            gz += bf2f(gx[512 + n]);
            gin += bf2f(gx[1024 + n]);
        }
        float r = sigm(gr + br);
        float z = sigm(gz + bz);
        float na = tanhf(gin + bin + r * (ahn[rr] + bhn));
        float hp = h_prev[(size_t)m * 512 + n];
        float ho = (1.0f - z) * na + z * hp;
        h_out[(size_t)m * 512 + n] = ho;
        h_out_bf[(size_t)m * 512 + n] = f2bf(ho);
    }
}

// ---------------------------------------------------------------------------
// Fused u-GEMV + attention. One block per b (grid 256, block 256).
__global__ __launch_bounds__(256) void attn_u_kernel(const float* __restrict__ h1,
                                                     const ush* __restrict__ wU,
                                                     const float* __restrict__ Ub,
                                                     const float* __restrict__ vw,
                                                     const ush* __restrict__ Ws_bf,
                                                     const ush* __restrict__ enc_bf,
                                                     ush* __restrict__ ctx_bf) {
    int b = blockIdx.x;
    int tid = threadIdx.x;
    int lane = tid & 63, wave = tid >> 6;
    __shared__ float hs[512];
    __shared__ float usm[512];
    __shared__ float sc[SS];
    // stage h1 row (fp32)
    {
        float2 hv = ((const float2*)(h1 + (size_t)b * 512))[tid];
        hs[tid * 2] = hv.x;
        hs[tid * 2 + 1] = hv.y;
    }
    __syncthreads();
    // u GEMV: thread computes cols 2t, 2t+1
    {
        int n0 = tid * 2;
        float a0 = 0.f, a1 = 0.f;
        const ush* w0 = wU + (size_t)n0 * 512;
        const ush* w1 = w0 + 512;
        for (int k = 0; k < 512; k += 8) {
            short8 wv0 = *(const short8*)(w0 + k);
            short8 wv1 = *(const short8*)(w1 + k);
#pragma unroll
            for (int j = 0; j < 8; j++) {
                float hf = hs[k + j];
                a0 += hf * bf2f((ush)wv0[j]);
                a1 += hf * bf2f((ush)wv1[j]);
            }
        }
        usm[n0] = a0 + Ub[n0];
        usm[n0 + 1] = a1 + Ub[n0 + 1];
    }
    __syncthreads();
    int col = lane * 8;
    float ur[8], vr[8];
#pragma unroll
    for (int q = 0; q < 8; q++) ur[q] = usm[col + q];
    {
        float4 v0 = *(const float4*)(vw + col);
        float4 v1 = *(const float4*)(vw + col + 4);
        vr[0] = v0.x; vr[1] = v0.y; vr[2] = v0.z; vr[3] = v0.w;
        vr[4] = v1.x; vr[5] = v1.y; vr[6] = v1.z; vr[7] = v1.w;
    }
    const ush* wsb = Ws_bf + (size_t)b * SS * HH;
#pragma unroll
    for (int gg = 0; gg < 4; gg++) {
        int s0 = wave * 32 + gg * 8;
        float p[8];
#pragma unroll
        for (int j = 0; j < 8; j++) {
            short8 rv = *(const short8*)(wsb + (size_t)(s0 + j) * HH + col);
            float acc = 0.0f;
#pragma unroll
            for (int q = 0; q < 8; q++) {
                float e = bf2f((ush)rv[q]) + ur[q];
                acc += fmaxf(e, 0.0f) * vr[q];
            }
            p[j] = acc;
        }
#pragma unroll
        for (int off = 32; off > 0; off >>= 1)
#pragma unroll
            for (int j = 0; j < 8; j++) p[j] += __shfl_xor(p[j], off);
        float out = p[0];
#pragma unroll
        for (int j = 1; j < 8; j++)
            if (lane == j) out = p[j];
        if (lane < 8) sc[s0 + lane] = out;
    }
    __syncthreads();
    if (wave == 0) {
        float s0v = sc[lane], s1v = sc[lane + 64];
        float m = wave_max(fmaxf(s0v, s1v));
        float e0 = expf(s0v - m), e1 = expf(s1v - m);
        float ssum = wave_sum(e0 + e1);
        float inv = 1.0f / ssum;
        sc[lane] = e0 * inv;
        sc[lane + 64] = e1 * inv;
    }
    __syncthreads();
    float ax = sc[lane * 2], ay = sc[lane * 2 + 1];
    const ush* eb = enc_bf + (size_t)b * CC * SS;
#pragma unroll
    for (int g = 0; g < 16; g++) {
        float p[8];
#pragma unroll
        for (int j = 0; j < 8; j++) {
            int c = wave * 128 + g * 8 + j;
            unsigned ev = *(const unsigned*)(eb + (size_t)c * SS + lane * 2);
            float flo = __uint_as_float(ev << 16);
            float fhi = __uint_as_float(ev & 0xFFFF0000u);
            p[j] = flo * ax + fhi * ay;
        }
#pragma unroll
        for (int off = 32; off > 0; off >>= 1)
#pragma unroll
            for (int j = 0; j < 8; j++) p[j] += __shfl_xor(p[j], off);
        float out = p[0];
#pragma unroll
        for (int j = 1; j < 8; j++)
            if (lane == j) out = p[j];
        if (lane < 8) ctx_bf[(size_t)b * CC + wave * 128 + g * 8 + lane] = f2bf(out);
    }
}

// ---------------------------------------------------------------------------
// fc: out_proj. 128 blocks, block 256. relu+bias, bf16 out (y and ys).
__global__ __launch_bounds__(256) void fc_kernel(const ush* __restrict__ ctx_bf,
                                                 const ush* __restrict__ h_bf,
                                                 const ush* __restrict__ wFc,
                                                 const float* __restrict__ fcb,
                                                 ush* __restrict__ y,
                                                 ush* __restrict__ ys) {
    int i = blockIdx.x;
    int tid = threadIdx.x;
    int wave = tid >> 6, lane = tid & 63;
    int quad = lane >> 4, l16 = lane & 15;
    int m0 = (i >> 3) * 16;
    int n0 = (i & 7) * 64 + wave * 16;
    const ush* wp = wFc + (size_t)(n0 + l16) * 1024 + quad * 8;
    const ush* xp = ctx_bf + (size_t)(m0 + l16) * 512 + quad * 8;
    f32x4 acc = (f32x4){0.f, 0.f, 0.f, 0.f};
    mfma_tile16(xp, wp, acc);
    xp = h_bf + (size_t)(m0 + l16) * 512 + quad * 8;
    mfma_tile16(xp, wp + 512, acc);
    int n = n0 + l16;
    float bia = fcb[n];
#pragma unroll
    for (int r = 0; r < 4; r++) {
        float v = fmaxf(acc[r] + bia, 0.0f);
        ush bv = f2bf(v);
        size_t off = (size_t)(m0 + quad * 4 + r) * 512 + n;
        y[off] = bv;
        if (ys) ys[off] = bv;
    }
}

// ---------------------------------------------------------------------------
// cls GEMM: M=5888, N=64, K=512. 92 blocks.
__global__ __launch_bounds__(256) void cls_kernel(const ush* __restrict__ ys_bf,
                                                  const ush* __restrict__ wCls,
                                                  float* __restrict__ logits) {
    int i = blockIdx.x;
    int tid = threadIdx.x;
    int wave = tid >> 6, lane = tid & 63;
    int quad = lane >> 4, l16 = lane & 15;
    int m0 = i * 64 + wave * 16;
    const ush* xp = ys_bf + (size_t)(m0 + l16) * 512 + quad * 8;
    const ush* wp = wCls + (size_t)l16 * 512 + quad * 8;
    f32x4 acc4[4];
#pragma unroll
    for (int s = 0; s < 4; s++) acc4[s] = (f32x4){0.f, 0.f, 0.f, 0.f};
    mfma_tile64(xp, wp, 512, acc4);
    float* Lb = logits + (size_t)(m0 + quad * 4) * 64 + l16;
#pragma unroll
    for (int s = 0; s < 4; s++)
#pragma unroll
        for (int rr = 0; rr < 4; rr++) Lb[(size_t)rr * 64 + s * 16] = acc4[s][rr];
}

// NLL over logits + cls bias. grid 256, block 256 (4 waves).
__global__ __launch_bounds__(256) void nll_kernel(const float* __restrict__ logits,
                                                  const float* __restrict__ cls_b,
                                                  const int* __restrict__ seq,
                                                  float* __restrict__ acc) {
    int tid = threadIdx.x;
    int wave = tid >> 6, lane = tid & 63;
    float biasv = cls_b[lane];
    float lsum = 0.0f, lcnt = 0.0f;
    for (int item = blockIdx.x * 4 + wave; item < 5888; item += gridDim.x * 4) {
        int t = item >> 8, b = item & 255;
        float v = logits[(size_t)item * 64 + lane] + biasv;
        float m = wave_max(v);
        float e = expf(v - m);
        float s = wave_sum(e);
        int label = seq[b * LL + t + 1];
        float vl = __shfl(v, label);
        if (lane == 0 && label > 0) {
            lsum += -(vl - m - logf(s));
            lcnt += 1.0f;
        }
    }
    if (lane == 0 && (lsum != 0.0f || lcnt != 0.0f)) {
        atomicAdd(&acc[0], lsum);
        atomicAdd(&acc[1], lcnt);
    }
}

__global__ void final_kernel(const float* __restrict__ acc, float* __restrict__ out) {
    if (threadIdx.x == 0) out[0] = acc[0] / acc[1];
}

// ---------------------------------------------------------------------------
extern "C" void kernel_launch(void* const* d_in, const int* in_sizes, int n_in,
                              void* d_out, int out_size, void* d_ws, size_t ws_size,
                              hipStream_t stream) {
    const float* enc        = (const float*)d_in[0];
    const int*   seq        = (const int*)d_in[1];
    const float* embed_w    = (const float*)d_in[3];
    const float* init_state = (const float*)d_in[4];
    const float* attn_W_w   = (const float*)d_in[5];
    const float* attn_W_b   = (const float*)d_in[6];
    const float* attn_U_w   = (const float*)d_in[7];
    const float* attn_U_b   = (const float*)d_in[8];
    const float* attn_v_w   = (const float*)d_in[9];
    const float* fc_w       = (const float*)d_in[11];
    const float* fc_b       = (const float*)d_in[12];
    const float* cls_w      = (const float*)d_in[13];
    const float* cls_b      = (const float*)d_in[14];
    const float* g0_wih     = (const float*)d_in[15];
    const float* g0_whh     = (const float*)d_in[16];
    const float* g0_bih     = (const float*)d_in[17];
    const float* g0_bhh     = (const float*)d_in[18];
    const float* g1_wih     = (const float*)d_in[19];
    const float* g1_whh     = (const float*)d_in[20];
    const float* g1_bih     = (const float*)d_in[21];
    const float* g1_bhh     = (const float*)d_in[22];
    float* out = (float*)d_out;

    float* ws = (float*)d_ws;
    size_t o = 0;
    ush* Ws_bf   = (ush*)(ws + o); o += (size_t)BB * SS * HH / 2;        // 8.39M
    ush* enc_bf  = (ush*)(ws + o); o += (size_t)BB * CC * SS / 2;        // 8.39M
    ush* ys_bf   = (ush*)(ws + o); o += (size_t)(LL - 1) * BB * HH / 2;  // 1.51M
    ush* xall_bf = (ush*)(ws + o); o += (size_t)(LL - 1) * BB * HH / 2;  // 1.51M
    ush* wWb  = (ush*)(ws + o); o += 262144 / 2;
    ush* wU   = (ush*)(ws + o); o += 262144 / 2;
    ush* wFc  = (ush*)(ws + o); o += 524288 / 2;
    ush* wCls = (ush*)(ws + o); o += 32768 / 2;
    ush* wG0i = (ush*)(ws + o); o += 1572864 / 2;
    ush* wG0h = (ush*)(ws + o); o += 786432 / 2;
    ush* wG1i = (ush*)(ws + o); o += 786432 / 2;
    ush* wG1h = (ush*)(ws + o); o += 786432 / 2;
    ush* Gx   = (ush*)(ws + o); o += (size_t)(LL - 1) * BB * 1536 / 2;   // 4.52M fl
    float* logits = (float*)Gx;  // alias: Gx dead after loop, logits 377K < 4.5M
    float* h0a    = ws + o; o += (size_t)BB * HH;
    float* h0b    = ws + o; o += (size_t)BB * HH;
    float* h1a    = ws + o; o += (size_t)BB * HH;
    float* h1b    = ws + o; o += (size_t)BB * HH;
    float* accb   = ws + o; o += 256;
    ush* h0a_bf = (ush*)(ws + o); o += (size_t)BB * HH / 2;
    ush* h0b_bf = (ush*)(ws + o); o += (size_t)BB * HH / 2;
    ush* h1a_bf = (ush*)(ws + o); o += (size_t)BB * HH / 2;
    ush* h1b_bf = (ush*)(ws + o); o += (size_t)BB * HH / 2;
    ush* y_bf   = (ush*)(ws + o); o += (size_t)BB * HH / 2;
    ush* ctx_bf = (ush*)(ws + o); o += (size_t)BB * CC / 2;

    // ---- prologue
    ConvAllArgs ca;
    ca.src[0] = attn_W_w; ca.dst[0] = wWb;
    ca.src[1] = attn_U_w; ca.dst[1] = wU;
    ca.src[2] = fc_w;     ca.dst[2] = wFc;
    ca.src[3] = cls_w;    ca.dst[3] = wCls;
    ca.src[4] = g0_wih;   ca.dst[4] = wG0i;
    ca.src[5] = g0_whh;   ca.dst[5] = wG0h;
    ca.src[6] = g1_wih;   ca.dst[6] = wG1i;
    ca.src[7] = g1_whh;   ca.dst[7] = wG1h;
    conv_all<<<4896, 256, 0, stream>>>(ca);
    conv_kernel<<<16384, 256, 0, stream>>>(enc, enc_bf, 4194304);
    gather_kernel<<<(LL - 1) * BB, 128, 0, stream>>>(embed_w, seq, xall_bf);
    ws_mfma<<<dim3(128, 8), 256, 0, stream>>>(enc, wWb, attn_W_b, Ws_bf);
    gx_mfma<<<dim3(92, 24), 256, 0, stream>>>(xall_bf, wG0i, Gx);
    init_kernel<<<512, 256, 0, stream>>>(init_state, h0a, h1a, h0a_bf, h1a_bf, accb);

    // y0 = out_proj(attn(h1), h1)
    attn_u_kernel<<<BB, 256, 0, stream>>>(h1a, wU, attn_U_b, attn_v_w, Ws_bf, enc_bf, ctx_bf);
    fc_kernel<<<128, 256, 0, stream>>>(ctx_bf, h1a_bf, wFc, fc_b, y_bf, nullptr);

    float* h0_in = h0a; float* h0_out = h0b;
    float* h1_in = h1a; float* h1_out = h1b;
    ush* h0_in_bf = h0a_bf; ush* h0_out_bf = h0b_bf;
    ush* h1_in_bf = h1a_bf; ush* h1_out_bf = h1b_bf;
    for (int t = 0; t < LL - 1; t++) {
        gru_fused<true, 1024><<<128, 256, 0, stream>>>(
            y_bf, h0_in_bf, wG0i, wG0h, Gx + (size_t)t * BB * 1536,
            g0_bih, g0_bhh, h0_in, h0_out, h0_out_bf);
        gru_fused<false, 512><<<128, 256, 0, stream>>>(
            h0_out_bf, h1_in_bf, wG1i, wG1h, nullptr,
            g1_bih, g1_bhh, h1_in, h1_out, h1_out_bf);
        attn_u_kernel<<<BB, 256, 0, stream>>>(h1_out, wU, attn_U_b, attn_v_w,
                                              Ws_bf, enc_bf, ctx_bf);
        fc_kernel<<<128, 256, 0, stream>>>(ctx_bf, h1_out_bf, wFc, fc_b, y_bf,
                                           ys_bf + (size_t)t * BB * HH);
        float* tf;
        tf = h0_in; h0_in = h0_out; h0_out = tf;
        tf = h1_in; h1_in = h1_out; h1_out = tf;
        ush* tb;
        tb = h0_in_bf; h0_in_bf = h0_out_bf; h0_out_bf = tb;
        tb = h1_in_bf; h1_in_bf = h1_out_bf; h1_out_bf = tb;
    }

    cls_kernel<<<92, 256, 0, stream>>>(ys_bf, wCls, logits);
    nll_kernel<<<256, 256, 0, stream>>>(logits, cls_b, seq, accb);
    final_kernel<<<1, 64, 0, stream>>>(accb, out);
}

// Round 7
// 2248.641 us; speedup vs baseline: 2.9036x; 1.1004x over previous
//
#include <hip/hip_runtime.h>
#include <hip/hip_bf16.h>
#include <cstddef>

// Problem dims (fixed)
#define BB 256
#define CC 512
#define SS 128      // FH*FW = 8*16
#define HH 512
#define VV 64
#define LL 24       // sequence length; steps = 23

typedef unsigned short ush;
typedef __attribute__((ext_vector_type(8))) short short8;
typedef __attribute__((ext_vector_type(4))) float f32x4;

__device__ __forceinline__ float wave_sum(float v) {
#pragma unroll
    for (int off = 32; off > 0; off >>= 1) v += __shfl_xor(v, off);
    return v;
}
__device__ __forceinline__ float wave_max(float v) {
#pragma unroll
    for (int off = 32; off > 0; off >>= 1) v = fmaxf(v, __shfl_xor(v, off));
    return v;
}
__device__ __forceinline__ float sigm(float x) { return 1.0f / (1.0f + expf(-x)); }
__device__ __forceinline__ ush f2bf(float f) {
    unsigned u = __float_as_uint(f);
    u += 0x7FFFu + ((u >> 16) & 1u);
    return (ush)(u >> 16);
}
__device__ __forceinline__ float bf2f(ush b) {
    return __uint_as_float(((unsigned)b) << 16);
}
__device__ __forceinline__ unsigned pack2(float a, float b) {
    return (unsigned)f2bf(a) | ((unsigned)f2bf(b) << 16);
}

// Swizzle 128 blocks -> (mg 0..3, cg 0..31) with cg%8 pinned to bid%8 (XCD affinity)
__device__ __forceinline__ void decomp128(int bid, int& mg, int& cg) {
    int q = bid & 7;
    int idx = bid >> 3;          // 0..15
    cg = q + 8 * (idx & 3);      // 0..31
    mg = idx >> 2;               // 0..3
}

// ---------------------------------------------------------------------------
// Fused weight conversion: 8 segments, one f4 per thread. Total 1253376 f4s.
struct ConvAllArgs {
    const float* src[8];
    ush* dst[8];
};
__global__ __launch_bounds__(256) void conv_all(ConvAllArgs a) {
    int i = blockIdx.x * 256 + threadIdx.x;
    int seg, base;
    if (i < 65536)        { seg = 0; base = 0; }
    else if (i < 131072)  { seg = 1; base = 65536; }
    else if (i < 262144)  { seg = 2; base = 131072; }
    else if (i < 270336)  { seg = 3; base = 262144; }
    else if (i < 663552)  { seg = 4; base = 270336; }
    else if (i < 860160)  { seg = 5; base = 663552; }
    else if (i < 1056768) { seg = 6; base = 860160; }
    else                  { seg = 7; base = 1056768; }
    int j = i - base;
    float4 v = ((const float4*)a.src[seg])[j];
    uint2 o;
    o.x = pack2(v.x, v.y);
    o.y = pack2(v.z, v.w);
    ((uint2*)a.dst[seg])[j] = o;
}

// fp32 -> bf16 convert (enc), 4 elems/thread
__global__ __launch_bounds__(256) void conv_kernel(const float* __restrict__ src,
                                                   ush* __restrict__ dst, int n4) {
    int i = blockIdx.x * 256 + threadIdx.x;
    if (i < n4) {
        float4 v = ((const float4*)src)[i];
        uint2 o;
        o.x = pack2(v.x, v.y);
        o.y = pack2(v.z, v.w);
        ((uint2*)dst)[i] = o;
    }
}

// gather embeddings -> bf16
__global__ __launch_bounds__(128) void gather_kernel(const float* __restrict__ embed_w,
                                                     const int* __restrict__ seq,
                                                     ush* __restrict__ xall) {
    int item = blockIdx.x;           // t*256 + m
    int t = item >> 8, m = item & 255;
    int row = seq[m * LL + t];
    float4 v = ((const float4*)(embed_w + (size_t)row * HH))[threadIdx.x];
    uint2 o;
    o.x = pack2(v.x, v.y);
    o.y = pack2(v.z, v.w);
    ((uint2*)(xall + (size_t)item * HH))[threadIdx.x] = o;
}

// init: h states fp32+bf16, zero acc
__global__ __launch_bounds__(256) void init_kernel(const float* __restrict__ is,
                                                   float* __restrict__ h0,
                                                   float* __restrict__ h1,
                                                   ush* __restrict__ h0b,
                                                   ush* __restrict__ h1b,
                                                   float* __restrict__ acc) {
    int idx = blockIdx.x * 256 + threadIdx.x;
    if (idx < BB * HH) {
        float a = is[idx & 511];
        float b = is[512 + (idx & 511)];
        h0[idx] = a; h1[idx] = b;
        h0b[idx] = f2bf(a); h1b[idx] = f2bf(b);
    }
    if (idx < 2) acc[idx] = 0.0f;
}

// ---------------------------------------------------------------------------
// MFMA tile helpers (proven layouts: A row=l16 k=quad*8+j; B row=l16 same;
// D col=l16, row=quad*4+r)
__device__ __forceinline__ void mfma_tile64(const ush* xp, const ush* wp, size_t wst,
                                            f32x4 acc[4]) {
    short8 a_c = *(const short8*)xp;
    short8 b0 = *(const short8*)(wp);
    short8 b1 = *(const short8*)(wp + 16 * wst);
    short8 b2 = *(const short8*)(wp + 32 * wst);
    short8 b3 = *(const short8*)(wp + 48 * wst);
#pragma unroll
    for (int ks = 0; ks < 16; ks++) {
        short8 a_n, c0, c1, c2, c3;
        if (ks < 15) {
            int k = (ks + 1) * 32;
            a_n = *(const short8*)(xp + k);
            c0 = *(const short8*)(wp + k);
            c1 = *(const short8*)(wp + 16 * wst + k);
            c2 = *(const short8*)(wp + 32 * wst + k);
            c3 = *(const short8*)(wp + 48 * wst + k);
        }
        acc[0] = __builtin_amdgcn_mfma_f32_16x16x32_bf16(a_c, b0, acc[0], 0, 0, 0);
        acc[1] = __builtin_amdgcn_mfma_f32_16x16x32_bf16(a_c, b1, acc[1], 0, 0, 0);
        acc[2] = __builtin_amdgcn_mfma_f32_16x16x32_bf16(a_c, b2, acc[2], 0, 0, 0);
        acc[3] = __builtin_amdgcn_mfma_f32_16x16x32_bf16(a_c, b3, acc[3], 0, 0, 0);
        if (ks < 15) { a_c = a_n; b0 = c0; b1 = c1; b2 = c2; b3 = c3; }
    }
}

__device__ __forceinline__ void mfma_tile16(const ush* xp, const ush* wp, f32x4& acc) {
#pragma unroll
    for (int ks = 0; ks < 16; ks++) {
        short8 a = *(const short8*)(xp + ks * 32);
        short8 b = *(const short8*)(wp + ks * 32);
        acc = __builtin_amdgcn_mfma_f32_16x16x32_bf16(a, b, acc, 0, 0, 0);
    }
}

// ---------------------------------------------------------------------------
// Ws MFMA (proven R3): grid (128, 8), block 256. Out bf16.
__global__ __launch_bounds__(256) void ws_mfma(const float* __restrict__ enc,
                                               const ush* __restrict__ Wb,
                                               const float* __restrict__ bias,
                                               ush* __restrict__ Ws_bf) {
    int tid = threadIdx.x;
    int wave = tid >> 6, lane = tid & 63;
    int quad = lane >> 4, l16 = lane & 15;
    int m0 = blockIdx.x * 256 + wave * 64;
    int n0 = blockIdx.y * 64;
    int b = m0 >> 7;
    int s_base = m0 & 127;
    const float* eb = enc + (size_t)b * CC * SS;
    const ush* wp = Wb + (size_t)(n0 + l16) * 512 + quad * 8;
    f32x4 acc[4][4];
#pragma unroll
    for (int f = 0; f < 4; f++)
#pragma unroll
        for (int s = 0; s < 4; s++) acc[f][s] = (f32x4){0.f, 0.f, 0.f, 0.f};
    for (int k0 = 0; k0 < 512; k0 += 32) {
        short8 af[4], bfr[4];
#pragma unroll
        for (int f = 0; f < 4; f++) {
            int s = s_base + f * 16 + l16;
#pragma unroll
            for (int j = 0; j < 8; j++) {
                float v = eb[(size_t)(k0 + quad * 8 + j) * SS + s];
                af[f][j] = (short)f2bf(v);
            }
        }
#pragma unroll
        for (int s = 0; s < 4; s++)
            bfr[s] = *(const short8*)(wp + (size_t)s * 16 * 512 + k0);
#pragma unroll
        for (int f = 0; f < 4; f++)
#pragma unroll
            for (int s = 0; s < 4; s++)
                acc[f][s] = __builtin_amdgcn_mfma_f32_16x16x32_bf16(af[f], bfr[s], acc[f][s], 0, 0, 0);
    }
#pragma unroll
    for (int f = 0; f < 4; f++)
#pragma unroll
        for (int s = 0; s < 4; s++)
#pragma unroll
            for (int r = 0; r < 4; r++) {
                int m = m0 + f * 16 + quad * 4 + r;
                int n = n0 + s * 16 + l16;
                Ws_bf[(size_t)m * HH + n] = f2bf(acc[f][s][r] + bias[n]);
            }
}

// ---------------------------------------------------------------------------
// GRU fused, m-grouped: block = 64 rows x 16 cols, grid 128 (XCD-swizzled).
// Wave w handles rows [mg*64 + w*16, +16). 4 acc chains: r, z, gi_n, gh_n.
// HASX (gru0): A = y (K 0:512 of wi) then x_t (K 512:1024); KI=1024.
// !HASX (gru1): A = xa only (K 0:512); KI=512.
template <bool HASX, int KI>
__global__ __launch_bounds__(256) void gru2(const ush* __restrict__ xa,
                                            const ush* __restrict__ xt,
                                            const ush* __restrict__ hA,
                                            const ush* __restrict__ wi,
                                            const ush* __restrict__ wh,
                                            const float* __restrict__ bih,
                                            const float* __restrict__ bhh,
                                            const float* __restrict__ h_prev,
                                            float* __restrict__ h_out,
                                            ush* __restrict__ h_out_bf) {
    int tid = threadIdx.x;
    int wave = tid >> 6, lane = tid & 63;
    int quad = lane >> 4, l16 = lane & 15;
    int mg, cg;
    decomp128(blockIdx.x, mg, cg);
    int m0 = mg * 64 + wave * 16;
    int nrow = cg * 16 + l16;                     // 0..511
    const ush* ap = xa + (size_t)(m0 + l16) * 512 + quad * 8;
    const ush* wr = wi + (size_t)nrow * KI + quad * 8;
    const ush* wz = wi + (size_t)(512 + nrow) * KI + quad * 8;
    const ush* wn = wi + (size_t)(1024 + nrow) * KI + quad * 8;
    const ush* hr = wh + (size_t)nrow * 512 + quad * 8;
    const ush* hz = wh + (size_t)(512 + nrow) * 512 + quad * 8;
    const ush* hn = wh + (size_t)(1024 + nrow) * 512 + quad * 8;
    f32x4 ar = (f32x4){0.f, 0.f, 0.f, 0.f};
    f32x4 az = ar, ain = ar, ahn = ar;
    // Phase A: xa against wi[:, 0:512]
#pragma unroll
    for (int ks = 0; ks < 16; ks++) {
        short8 a = *(const short8*)(ap + ks * 32);
        ar  = __builtin_amdgcn_mfma_f32_16x16x32_bf16(a, *(const short8*)(wr + ks * 32), ar, 0, 0, 0);
        az  = __builtin_amdgcn_mfma_f32_16x16x32_bf16(a, *(const short8*)(wz + ks * 32), az, 0, 0, 0);
        ain = __builtin_amdgcn_mfma_f32_16x16x32_bf16(a, *(const short8*)(wn + ks * 32), ain, 0, 0, 0);
    }
    if (HASX) {
        // Phase A2: x_t against wi[:, 512:1024]
        const ush* xp = xt + (size_t)(m0 + l16) * 512 + quad * 8;
#pragma unroll
        for (int ks = 0; ks < 16; ks++) {
            short8 a = *(const short8*)(xp + ks * 32);
            ar  = __builtin_amdgcn_mfma_f32_16x16x32_bf16(a, *(const short8*)(wr + 512 + ks * 32), ar, 0, 0, 0);
            az  = __builtin_amdgcn_mfma_f32_16x16x32_bf16(a, *(const short8*)(wz + 512 + ks * 32), az, 0, 0, 0);
            ain = __builtin_amdgcn_mfma_f32_16x16x32_bf16(a, *(const short8*)(wn + 512 + ks * 32), ain, 0, 0, 0);
        }
    }
    // Phase B: h_prev against wh
    {
        const ush* hp = hA + (size_t)(m0 + l16) * 512 + quad * 8;
#pragma unroll
        for (int ks = 0; ks < 16; ks++) {
            short8 a = *(const short8*)(hp + ks * 32);
            ar  = __builtin_amdgcn_mfma_f32_16x16x32_bf16(a, *(const short8*)(hr + ks * 32), ar, 0, 0, 0);
            az  = __builtin_amdgcn_mfma_f32_16x16x32_bf16(a, *(const short8*)(hz + ks * 32), az, 0, 0, 0);
            ahn = __builtin_amdgcn_mfma_f32_16x16x32_bf16(a, *(const short8*)(hn + ks * 32), ahn, 0, 0, 0);
        }
    }
    int n = nrow;
    float br = bih[n] + bhh[n];
    float bz = bih[512 + n] + bhh[512 + n];
    float bin = bih[1024 + n];
    float bhn = bhh[1024 + n];
#pragma unroll
    for (int rr = 0; rr < 4; rr++) {
        int m = m0 + quad * 4 + rr;
        float r = sigm(ar[rr] + br);
        float z = sigm(az[rr] + bz);
        float na = tanhf(ain[rr] + bin + r * (ahn[rr] + bhn));
        float hp = h_prev[(size_t)m * 512 + n];
        float ho = (1.0f - z) * na + z * hp;
        h_out[(size_t)m * 512 + n] = ho;
        h_out_bf[(size_t)m * 512 + n] = f2bf(ho);
    }
}

// ---------------------------------------------------------------------------
// u GEMM: u = h1' @ wU^T + Ub. Block = 64m x 16n, grid 128 (swizzled). fp32 out.
__global__ __launch_bounds__(256) void u_mfma(const ush* __restrict__ h_bf,
                                              const ush* __restrict__ wU,
                                              const float* __restrict__ Ub,
                                              float* __restrict__ u) {
    int tid = threadIdx.x;
    int wave = tid >> 6, lane = tid & 63;
    int quad = lane >> 4, l16 = lane & 15;
    int mg, cg;
    decomp128(blockIdx.x, mg, cg);
    int m0 = mg * 64 + wave * 16;
    int n = cg * 16 + l16;
    const ush* xp = h_bf + (size_t)(m0 + l16) * 512 + quad * 8;
    const ush* wp = wU + (size_t)n * 512 + quad * 8;
    f32x4 acc = (f32x4){0.f, 0.f, 0.f, 0.f};
    mfma_tile16(xp, wp, acc);
    float bia = Ub[n];
#pragma unroll
    for (int r = 0; r < 4; r++)
        u[(size_t)(m0 + quad * 4 + r) * 512 + n] = acc[r] + bia;
}

// ---------------------------------------------------------------------------
// Attention (no weights, u precomputed): one block per b, grid 256.
__global__ __launch_bounds__(256) void attn2(const float* __restrict__ u,
                                             const float* __restrict__ vw,
                                             const ush* __restrict__ Ws_bf,
                                             const ush* __restrict__ enc_bf,
                                             ush* __restrict__ ctx_bf) {
    int b = blockIdx.x;
    int tid = threadIdx.x;
    int lane = tid & 63, wave = tid >> 6;
    __shared__ float sc[SS];
    int col = lane * 8;
    float ur[8], vr[8];
    {
        float4 u0 = *(const float4*)(u + (size_t)b * 512 + col);
        float4 u1 = *(const float4*)(u + (size_t)b * 512 + col + 4);
        ur[0] = u0.x; ur[1] = u0.y; ur[2] = u0.z; ur[3] = u0.w;
        ur[4] = u1.x; ur[5] = u1.y; ur[6] = u1.z; ur[7] = u1.w;
        float4 v0 = *(const float4*)(vw + col);
        float4 v1 = *(const float4*)(vw + col + 4);
        vr[0] = v0.x; vr[1] = v0.y; vr[2] = v0.z; vr[3] = v0.w;
        vr[4] = v1.x; vr[5] = v1.y; vr[6] = v1.z; vr[7] = v1.w;
    }
    const ush* wsb = Ws_bf + (size_t)b * SS * HH;
#pragma unroll
    for (int gg = 0; gg < 4; gg++) {
        int s0 = wave * 32 + gg * 8;
        float p[8];
#pragma unroll
        for (int j = 0; j < 8; j++) {
            short8 rv = *(const short8*)(wsb + (size_t)(s0 + j) * HH + col);
            float acc = 0.0f;
#pragma unroll
            for (int q = 0; q < 8; q++) {
                float e = bf2f((ush)rv[q]) + ur[q];
                acc += fmaxf(e, 0.0f) * vr[q];
            }
            p[j] = acc;
        }
#pragma unroll
        for (int off = 32; off > 0; off >>= 1)
#pragma unroll
            for (int j = 0; j < 8; j++) p[j] += __shfl_xor(p[j], off);
        float out = p[0];
#pragma unroll
        for (int j = 1; j < 8; j++)
            if (lane == j) out = p[j];
        if (lane < 8) sc[s0 + lane] = out;
    }
    __syncthreads();
    if (wave == 0) {
        float s0v = sc[lane], s1v = sc[lane + 64];
        float m = wave_max(fmaxf(s0v, s1v));
        float e0 = expf(s0v - m), e1 = expf(s1v - m);
        float ssum = wave_sum(e0 + e1);
        float inv = 1.0f / ssum;
        sc[lane] = e0 * inv;
        sc[lane + 64] = e1 * inv;
    }
    __syncthreads();
    float ax = sc[lane * 2], ay = sc[lane * 2 + 1];
    const ush* eb = enc_bf + (size_t)b * CC * SS;
#pragma unroll
    for (int g = 0; g < 16; g++) {
        float p[8];
#pragma unroll
        for (int j = 0; j < 8; j++) {
            int c = wave * 128 + g * 8 + j;
            unsigned ev = *(const unsigned*)(eb + (size_t)c * SS + lane * 2);
            float flo = __uint_as_float(ev << 16);
            float fhi = __uint_as_float(ev & 0xFFFF0000u);
            p[j] = flo * ax + fhi * ay;
        }
#pragma unroll
        for (int off = 32; off > 0; off >>= 1)
#pragma unroll
            for (int j = 0; j < 8; j++) p[j] += __shfl_xor(p[j], off);
        float out = p[0];
#pragma unroll
        for (int j = 1; j < 8; j++)
            if (lane == j) out = p[j];
        if (lane < 8) ctx_bf[(size_t)b * CC + wave * 128 + g * 8 + lane] = f2bf(out);
    }
}

// ---------------------------------------------------------------------------
// fc: out_proj. Block = 64m x 16n, grid 128 (swizzled). relu+bias, bf16 out.
__global__ __launch_bounds__(256) void fc2(const ush* __restrict__ ctx_bf,
                                           const ush* __restrict__ h_bf,
                                           const ush* __restrict__ wFc,
                                           const float* __restrict__ fcb,
                                           ush* __restrict__ y,
                                           ush* __restrict__ ys) {
    int tid = threadIdx.x;
    int wave = tid >> 6, lane = tid & 63;
    int quad = lane >> 4, l16 = lane & 15;
    int mg, cg;
    decomp128(blockIdx.x, mg, cg);
    int m0 = mg * 64 + wave * 16;
    int n = cg * 16 + l16;
    const ush* wp = wFc + (size_t)n * 1024 + quad * 8;
    const ush* xp = ctx_bf + (size_t)(m0 + l16) * 512 + quad * 8;
    f32x4 acc = (f32x4){0.f, 0.f, 0.f, 0.f};
    mfma_tile16(xp, wp, acc);
    xp = h_bf + (size_t)(m0 + l16) * 512 + quad * 8;
    mfma_tile16(xp, wp + 512, acc);
    float bia = fcb[n];
#pragma unroll
    for (int r = 0; r < 4; r++) {
        float v = fmaxf(acc[r] + bia, 0.0f);
        ush bv = f2bf(v);
        size_t off = (size_t)(m0 + quad * 4 + r) * 512 + n;
        y[off] = bv;
        if (ys) ys[off] = bv;
    }
}

// ---------------------------------------------------------------------------
// cls GEMM: M=5888, N=64, K=512. 92 blocks.
__global__ __launch_bounds__(256) void cls_kernel(const ush* __restrict__ ys_bf,
                                                  const ush* __restrict__ wCls,
                                                  float* __restrict__ logits) {
    int i = blockIdx.x;
    int tid = threadIdx.x;
    int wave = tid >> 6, lane = tid & 63;
    int quad = lane >> 4, l16 = lane & 15;
    int m0 = i * 64 + wave * 16;
    const ush* xp = ys_bf + (size_t)(m0 + l16) * 512 + quad * 8;
    const ush* wp = wCls + (size_t)l16 * 512 + quad * 8;
    f32x4 acc4[4];
#pragma unroll
    for (int s = 0; s < 4; s++) acc4[s] = (f32x4){0.f, 0.f, 0.f, 0.f};
    mfma_tile64(xp, wp, 512, acc4);
    float* Lb = logits + (size_t)(m0 + quad * 4) * 64 + l16;
#pragma unroll
    for (int s = 0; s < 4; s++)
#pragma unroll
        for (int rr = 0; rr < 4; rr++) Lb[(size_t)rr * 64 + s * 16] = acc4[s][rr];
}

// NLL over logits + cls bias. grid 256, block 256 (4 waves).
__global__ __launch_bounds__(256) void nll_kernel(const float* __restrict__ logits,
                                                  const float* __restrict__ cls_b,
                                                  const int* __restrict__ seq,
                                                  float* __restrict__ acc) {
    int tid = threadIdx.x;
    int wave = tid >> 6, lane = tid & 63;
    float biasv = cls_b[lane];
    float lsum = 0.0f, lcnt = 0.0f;
    for (int item = blockIdx.x * 4 + wave; item < 5888; item += gridDim.x * 4) {
        int t = item >> 8, b = item & 255;
        float v = logits[(size_t)item * 64 + lane] + biasv;
        float m = wave_max(v);
        float e = expf(v - m);
        float s = wave_sum(e);
        int label = seq[b * LL + t + 1];
        float vl = __shfl(v, label);
        if (lane == 0 && label > 0) {
            lsum += -(vl - m - logf(s));
            lcnt += 1.0f;
        }
    }
    if (lane == 0 && (lsum != 0.0f || lcnt != 0.0f)) {
        atomicAdd(&acc[0], lsum);
        atomicAdd(&acc[1], lcnt);
    }
}

__global__ void final_kernel(const float* __restrict__ acc, float* __restrict__ out) {
    if (threadIdx.x == 0) out[0] = acc[0] / acc[1];
}

// ---------------------------------------------------------------------------
extern "C" void kernel_launch(void* const* d_in, const int* in_sizes, int n_in,
                              void* d_out, int out_size, void* d_ws, size_t ws_size,
                              hipStream_t stream) {
    const float* enc        = (const float*)d_in[0];
    const int*   seq        = (const int*)d_in[1];
    const float* embed_w    = (const float*)d_in[3];
    const float* init_state = (const float*)d_in[4];
    const float* attn_W_w   = (const float*)d_in[5];
    const float* attn_W_b   = (const float*)d_in[6];
    const float* attn_U_w   = (const float*)d_in[7];
    const float* attn_U_b   = (const float*)d_in[8];
    const float* attn_v_w   = (const float*)d_in[9];
    const float* fc_w       = (const float*)d_in[11];
    const float* fc_b       = (const float*)d_in[12];
    const float* cls_w      = (const float*)d_in[13];
    const float* cls_b      = (const float*)d_in[14];
    const float* g0_wih     = (const float*)d_in[15];
    const float* g0_whh     = (const float*)d_in[16];
    const float* g0_bih     = (const float*)d_in[17];
    const float* g0_bhh     = (const float*)d_in[18];
    const float* g1_wih     = (const float*)d_in[19];
    const float* g1_whh     = (const float*)d_in[20];
    const float* g1_bih     = (const float*)d_in[21];
    const float* g1_bhh     = (const float*)d_in[22];
    float* out = (float*)d_out;

    float* ws = (float*)d_ws;
    size_t o = 0;
    ush* Ws_bf   = (ush*)(ws + o); o += (size_t)BB * SS * HH / 2;        // 8.39M fl
    ush* enc_bf  = (ush*)(ws + o); o += (size_t)BB * CC * SS / 2;        // 8.39M fl
    ush* ys_bf   = (ush*)(ws + o); o += (size_t)(LL - 1) * BB * HH / 2;  // 1.51M
    ush* xall_bf = (ush*)(ws + o); o += (size_t)(LL - 1) * BB * HH / 2;  // 1.51M
    ush* wWb  = (ush*)(ws + o); o += 262144 / 2;
    ush* wU   = (ush*)(ws + o); o += 262144 / 2;
    ush* wFc  = (ush*)(ws + o); o += 524288 / 2;
    ush* wCls = (ush*)(ws + o); o += 32768 / 2;
    ush* wG0i = (ush*)(ws + o); o += 1572864 / 2;
    ush* wG0h = (ush*)(ws + o); o += 786432 / 2;
    ush* wG1i = (ush*)(ws + o); o += 786432 / 2;
    ush* wG1h = (ush*)(ws + o); o += 786432 / 2;
    float* u      = ws + o; o += (size_t)BB * HH;
    float* logits = ws + o; o += (size_t)(LL - 1) * BB * VV;
    float* h0a    = ws + o; o += (size_t)BB * HH;
    float* h0b    = ws + o; o += (size_t)BB * HH;
    float* h1a    = ws + o; o += (size_t)BB * HH;
    float* h1b    = ws + o; o += (size_t)BB * HH;
    float* accb   = ws + o; o += 256;
    ush* h0a_bf = (ush*)(ws + o); o += (size_t)BB * HH / 2;
    ush* h0b_bf = (ush*)(ws + o); o += (size_t)BB * HH / 2;
    ush* h1a_bf = (ush*)(ws + o); o += (size_t)BB * HH / 2;
    ush* h1b_bf = (ush*)(ws + o); o += (size_t)BB * HH / 2;
    ush* y_bf   = (ush*)(ws + o); o += (size_t)BB * HH / 2;
    ush* ctx_bf = (ush*)(ws + o); o += (size_t)BB * CC / 2;

    // ---- prologue
    ConvAllArgs ca;
    ca.src[0] = attn_W_w; ca.dst[0] = wWb;
    ca.src[1] = attn_U_w; ca.dst[1] = wU;
    ca.src[2] = fc_w;     ca.dst[2] = wFc;
    ca.src[3] = cls_w;    ca.dst[3] = wCls;
    ca.src[4] = g0_wih;   ca.dst[4] = wG0i;
    ca.src[5] = g0_whh;   ca.dst[5] = wG0h;
    ca.src[6] = g1_wih;   ca.dst[6] = wG1i;
    ca.src[7] = g1_whh;   ca.dst[7] = wG1h;
    conv_all<<<4896, 256, 0, stream>>>(ca);
    conv_kernel<<<16384, 256, 0, stream>>>(enc, enc_bf, 4194304);
    gather_kernel<<<(LL - 1) * BB, 128, 0, stream>>>(embed_w, seq, xall_bf);
    ws_mfma<<<dim3(128, 8), 256, 0, stream>>>(enc, wWb, attn_W_b, Ws_bf);
    init_kernel<<<512, 256, 0, stream>>>(init_state, h0a, h1a, h0a_bf, h1a_bf, accb);

    // y0 = out_proj(attn(h1), h1)
    u_mfma<<<128, 256, 0, stream>>>(h1a_bf, wU, attn_U_b, u);
    attn2<<<BB, 256, 0, stream>>>(u, attn_v_w, Ws_bf, enc_bf, ctx_bf);
    fc2<<<128, 256, 0, stream>>>(ctx_bf, h1a_bf, wFc, fc_b, y_bf, nullptr);

    float* h0_in = h0a; float* h0_out = h0b;
    float* h1_in = h1a; float* h1_out = h1b;
    ush* h0_in_bf = h0a_bf; ush* h0_out_bf = h0b_bf;
    ush* h1_in_bf = h1a_bf; ush* h1_out_bf = h1b_bf;
    for (int t = 0; t < LL - 1; t++) {
        gru2<true, 1024><<<128, 256, 0, stream>>>(
            y_bf, xall_bf + (size_t)t * BB * HH, h0_in_bf,
            wG0i, wG0h, g0_bih, g0_bhh, h0_in, h0_out, h0_out_bf);
        gru2<false, 512><<<128, 256, 0, stream>>>(
            h0_out_bf, nullptr, h1_in_bf,
            wG1i, wG1h, g1_bih, g1_bhh, h1_in, h1_out, h1_out_bf);
        u_mfma<<<128, 256, 0, stream>>>(h1_out_bf, wU, attn_U_b, u);
        attn2<<<BB, 256, 0, stream>>>(u, attn_v_w, Ws_bf, enc_bf, ctx_bf);
        fc2<<<128, 256, 0, stream>>>(ctx_bf, h1_out_bf, wFc, fc_b, y_bf,
                                     ys_bf + (size_t)t * BB * HH);
        float* tf;
        tf = h0_in; h0_in = h0_out; h0_out = tf;
        tf = h1_in; h1_in = h1_out; h1_out = tf;
        ush* tb;
        tb = h0_in_bf; h0_in_bf = h0_out_bf; h0_out_bf = tb;
        tb = h1_in_bf; h1_in_bf = h1_out_bf; h1_out_bf = tb;
    }

    cls_kernel<<<92, 256, 0, stream>>>(ys_bf, wCls, logits);
    nll_kernel<<<256, 256, 0, stream>>>(logits, cls_b, seq, accb);
    final_kernel<<<1, 64, 0, stream>>>(accb, out);
}